// Round 1
// baseline (238.209 us; speedup 1.0000x reference)
//
#include <hip/hip_runtime.h>

// Xonv2D: location-dependent 3x3 conv.
//   x:       (B=4, CIN=16, H=128, W=128)  fp32   -- 4 MB, L2/L3-resident
//   weights: (H, W, COUT=16, CIN=16, 3, 3) fp32  -- 151 MB, the traffic driver
//   bias:    (H, W, COUT) fp32
//   out:     (B, COUT, H, W) fp32
//
// V6: persistent 8-site-per-wave pipeline with global_load_lds DMA.
//  v5 was one-site-per-wave: each wave issued its 9 weight loads, stalled
//  ~900cy on HBM latency, computed ~700cy, exited. The VMEM pipe was bursty
//  (load burst -> drain -> compute -> exit), holding the 151MB weight stream
//  to ~3.2 TB/s. Now each wave owns 8 CONSECUTIVE sites (72KB contiguous
//  weight stream) and runs a depth-1 software pipeline: while computing
//  site s from LDS buffer p, the 9 global_load_lds_dwordx4 for site s+1 are
//  in flight into buffer 1-p. Per-wave ~9KB outstanding most of the time
//  -> per-CU in-flight ~50KB >> the ~9.2KB Little's-law need for 6.3 TB/s.
//  global_load_lds also deletes the 9 ds_write_b128 + 36 staging VGPRs of
//  v5 (staging layout is exactly the linear lane*16 pattern the DMA wants).
//  Wave-private buffers -> NO barrier anywhere; one asm vmcnt(0) per site
//  (by then the prefetch has had a full compute phase to land).
//
//  Grid: 1024 blocks x 128 thr (2 waves). 36KB LDS/block -> 4 blocks/CU,
//  exactly 4*256 = 1024 resident: single launch round, no tail.
//
// Kept from v5: coalesced weight fetch order (lane l takes f4 j*64+l),
// wave-local LDS transpose read ((o,g) 36-float fragment via ds_read_b128),
// x rows as dword-aligned float4 with w<=125 fast path, wave-uniform border
// path, XCD banding, butterfly reduce + single store.

#define HWD   128
#define CIND  16
#define COUTD 16
#define BATCH 4
#define SPW   8     // sites per wave (consecutive in w-major order)
#define WPB   2     // waves per block

typedef float f4  __attribute__((ext_vector_type(4)));
typedef float f4u __attribute__((ext_vector_type(4), aligned(4)));

// async DMA: 16B per lane, LDS dest = wave-uniform base + lane*16 (linear).
__device__ __forceinline__ void gload_lds16(const f4* gsrc, f4* ldst) {
    __builtin_amdgcn_global_load_lds(
        (const __attribute__((address_space(1))) unsigned int*)gsrc,
        (__attribute__((address_space(3))) unsigned int*)ldst,
        16, 0, 0);
}

__global__ __launch_bounds__(128) void xonv2d_kernel(
    const float* __restrict__ x,
    const float* __restrict__ wts,
    const float* __restrict__ bias,
    float* __restrict__ out)
{
    __shared__ f4 wsm[WPB][2][576];   // 2 waves x 2 buffers x 9216 B = 36 KB

    const int lane = threadIdx.x & 63;
    const int wave = threadIdx.x >> 6;

    // XCD banding: XCD k = blockIdx%8 handles sites [k*2048, (k+1)*2048).
    const int xcd = blockIdx.x & 7;
    const int idx = blockIdx.x >> 3;                      // 0..127 within band
    const int site0 = xcd * 2048 + (idx * WPB + wave) * SPW;

    const int o  = lane & 15;    // output channel
    const int g  = lane >> 4;    // channel group: c in [4g, 4g+4)
    const int c0 = g * 4;

    // ---- prologue: DMA site0's 9216B block into buffer 0 ----
    {
        const f4* gw = (const f4*)wts + (size_t)site0 * 576;
        #pragma unroll
        for (int j = 0; j < 9; ++j)
            gload_lds16(gw + j * 64 + lane, &wsm[wave][0][j * 64]);
    }

    int cur = 0;
    #pragma unroll 1
    for (int s = 0; s < SPW; ++s) {
        const int site = site0 + s;
        const int h = site >> 7;
        const int w = site & 127;

        // buffer `cur` ready after this (prefetch was issued one full
        // compute phase ago; residual wait is small).
        asm volatile("s_waitcnt vmcnt(0)" ::: "memory");

        // ---- issue next site's DMA into the other buffer (depth-1) ----
        if (s + 1 < SPW) {
            const f4* gw = (const f4*)wts + (size_t)(site + 1) * 576;
            #pragma unroll
            for (int j = 0; j < 9; ++j)
                gload_lds16(gw + j * 64 + lane, &wsm[wave][cur ^ 1][j * 64]);
        }

        // bias: one dword load, consumed only at the store (fully hidden)
        const float bv = bias[(size_t)site * COUTD + o];

        // ---- wave-local transpose read: per-lane (o,g) 36-float fragment ----
        f4 wv[9];
        {
            const f4* lp = &wsm[wave][cur][o * 36 + g * 9];
            #pragma unroll
            for (int j = 0; j < 9; ++j) wv[j] = lp[j];   // ds_read_b128
        }
        const float* wf = (const float*)wv;

        float acc[BATCH] = {0.f, 0.f, 0.f, 0.f};

        // w <= 125: float4 row loads read cols w-1..w+2 <= 127, in-bounds.
        const bool interior = (h >= 1) & (h <= HWD - 2) & (w >= 1) & (w <= HWD - 3);

        if (interior) {
            #pragma unroll
            for (int cc = 0; cc < 4; ++cc) {
                #pragma unroll
                for (int b = 0; b < BATCH; ++b) {
                    const float* xb = x + (((size_t)(b * CIND + c0 + cc) * HWD + (h - 1)) * HWD) + (w - 1);
                    f4 r0 = *(const f4u*)(xb);
                    f4 r1 = *(const f4u*)(xb + HWD);
                    f4 r2 = *(const f4u*)(xb + 2 * HWD);
                    const float* wr = wf + cc * 9;
                    acc[b] = fmaf(r0.x, wr[0], acc[b]);
                    acc[b] = fmaf(r0.y, wr[1], acc[b]);
                    acc[b] = fmaf(r0.z, wr[2], acc[b]);
                    acc[b] = fmaf(r1.x, wr[3], acc[b]);
                    acc[b] = fmaf(r1.y, wr[4], acc[b]);
                    acc[b] = fmaf(r1.z, wr[5], acc[b]);
                    acc[b] = fmaf(r2.x, wr[6], acc[b]);
                    acc[b] = fmaf(r2.y, wr[7], acc[b]);
                    acc[b] = fmaf(r2.z, wr[8], acc[b]);
                }
            }
        } else {
            #pragma unroll
            for (int cc = 0; cc < 4; ++cc) {
                #pragma unroll
                for (int b = 0; b < BATCH; ++b) {
                    const float* xb = x + ((size_t)(b * CIND + c0 + cc)) * (HWD * HWD);
                    #pragma unroll
                    for (int kh = 0; kh < 3; ++kh) {
                        const int hy = h + kh - 1;
                        #pragma unroll
                        for (int kw = 0; kw < 3; ++kw) {
                            const int wx = w + kw - 1;
                            const bool ok = (hy >= 0) & (hy < HWD) & (wx >= 0) & (wx < HWD);
                            const float xv = ok ? xb[hy * HWD + wx] : 0.f;
                            acc[b] = fmaf(xv, wf[cc * 9 + kh * 3 + kw], acc[b]);
                        }
                    }
                }
            }
        }

        // ---- butterfly reduce over the 4 c-groups ----
        float r[BATCH];
        #pragma unroll
        for (int b = 0; b < BATCH; ++b) {
            float v = acc[b];
            v += __shfl_xor(v, 32);
            v += __shfl_xor(v, 16);
            r[b] = v;
        }

        // lane (g,o) stores batch b = g: one store, all 64 lanes active
        const float vout = (g == 0) ? r[0] : (g == 1) ? r[1] : (g == 2) ? r[2] : r[3];
        out[((size_t)(g * COUTD + o)) * (HWD * HWD) + h * HWD + w] = vout + bv;

        cur ^= 1;
    }
}

extern "C" void kernel_launch(void* const* d_in, const int* in_sizes, int n_in,
                              void* d_out, int out_size, void* d_ws, size_t ws_size,
                              hipStream_t stream) {
    const float* x    = (const float*)d_in[0];
    const float* wts  = (const float*)d_in[1];
    const float* bias = (const float*)d_in[2];
    float* out = (float*)d_out;

    // 16384 sites / (2 waves * 8 sites) = 1024 blocks of 128 threads.
    // 36KB LDS -> 4 blocks/CU, exactly 1024 resident: no rounds, no tail.
    const int blocks = (HWD * HWD) / (WPB * SPW);
    xonv2d_kernel<<<blocks, WPB * 64, 0, stream>>>(x, wts, bias, out);
}